// Round 1
// baseline (698.774 us; speedup 1.0000x reference)
//
#include <hip/hip_runtime.h>
#include <climits>

// Sparse 3D max-pool (kernel=stride=2) via segmented atomic max.
// N=1e6 points, C=64 f32 channels, coords in [0,128)^3 -> 64^3 segments.

#define CHANNELS 64
#define COARSE_RES 64

// Order-preserving float -> signed-int key (involution).
__device__ __forceinline__ int float_key(float x) {
    int b = __float_as_int(x);
    return b ^ ((b >> 31) & 0x7fffffff);
}

__global__ void init_keys_kernel(int4* __restrict__ out, int n4) {
    int i = blockIdx.x * blockDim.x + threadIdx.x;
    int stride = gridDim.x * blockDim.x;
    const int4 v = make_int4(INT_MIN, INT_MIN, INT_MIN, INT_MIN);
    for (; i < n4; i += stride) out[i] = v;
}

// One thread handles 4 consecutive channels of one point.
__global__ void pool_atomic_kernel(const float4* __restrict__ feat,
                                   const int* __restrict__ coords,
                                   int* __restrict__ out, int npoints) {
    int idx = blockIdx.x * blockDim.x + threadIdx.x;
    int stride = gridDim.x * blockDim.x;
    int total = npoints * (CHANNELS / 4);
    for (; idx < total; idx += stride) {
        int p  = idx >> 4;       // point index (CHANNELS/4 == 16 groups per point)
        int c4 = idx & 15;       // 4-channel group
        int ci = coords[p * 3 + 0] >> 1;
        int cj = coords[p * 3 + 1] >> 1;
        int ck = coords[p * 3 + 2] >> 1;
        int seg = (ci * COARSE_RES + cj) * COARSE_RES + ck;
        float4 f = feat[p * 16 + c4];
        int* dst = out + seg * CHANNELS + c4 * 4;
        atomicMax(dst + 0, float_key(f.x));
        atomicMax(dst + 1, float_key(f.y));
        atomicMax(dst + 2, float_key(f.z));
        atomicMax(dst + 3, float_key(f.w));
    }
}

// In-place: int key -> float; INT_MIN sentinel (empty voxel) -> 0.
__global__ void decode_kernel(int4* __restrict__ out, int n4) {
    int i = blockIdx.x * blockDim.x + threadIdx.x;
    int stride = gridDim.x * blockDim.x;
    for (; i < n4; i += stride) {
        int4 k = out[i];
        float4 f;
        f.x = (k.x == INT_MIN) ? 0.0f : __int_as_float(k.x ^ ((k.x >> 31) & 0x7fffffff));
        f.y = (k.y == INT_MIN) ? 0.0f : __int_as_float(k.y ^ ((k.y >> 31) & 0x7fffffff));
        f.z = (k.z == INT_MIN) ? 0.0f : __int_as_float(k.z ^ ((k.z >> 31) & 0x7fffffff));
        f.w = (k.w == INT_MIN) ? 0.0f : __int_as_float(k.w ^ ((k.w >> 31) & 0x7fffffff));
        reinterpret_cast<float4*>(out)[i] = f;
    }
}

extern "C" void kernel_launch(void* const* d_in, const int* in_sizes, int n_in,
                              void* d_out, int out_size, void* d_ws, size_t ws_size,
                              hipStream_t stream) {
    const float4* feat = (const float4*)d_in[0];
    const int* coords  = (const int*)d_in[1];
    int npoints = in_sizes[0] / CHANNELS;          // 1,000,000
    int n_out   = out_size;                        // 262144 * 64 = 16,777,216
    int n4      = n_out / 4;                       // 4,194,304 int4s

    const int BLOCK = 256;
    int grid_init = min((n4 + BLOCK - 1) / BLOCK, 4096);
    init_keys_kernel<<<grid_init, BLOCK, 0, stream>>>((int4*)d_out, n4);

    int total_threads = npoints * (CHANNELS / 4);  // 16M
    int grid_pool = min((total_threads + BLOCK - 1) / BLOCK, 8192);
    pool_atomic_kernel<<<grid_pool, BLOCK, 0, stream>>>(feat, coords, (int*)d_out, npoints);

    decode_kernel<<<grid_init, BLOCK, 0, stream>>>((int4*)d_out, n4);
}

// Round 2
// 234.782 us; speedup vs baseline: 2.9763x; 2.9763x over previous
//
#include <hip/hip_runtime.h>
#include <math.h>

// Sparse 3D max-pool (kernel=stride=2), gather formulation.
// Phase A: CSR binning of 1M points into 64^3=262144 segments
//          (histogram -> exclusive scan -> index scatter), all in d_ws.
// Phase B: one wave per segment gathers its points' features (lane=channel),
//          register fmax reduce, single coalesced output write.

#define CHANNELS 64
#define COARSE_RES 64
#define NSEG (COARSE_RES * COARSE_RES * COARSE_RES)  // 262144
#define SCAN_BLOCKS (NSEG / 256)                     // 1024

__device__ __forceinline__ int seg_of(const int* __restrict__ coords, int p) {
    int ci = coords[p * 3 + 0] >> 1;
    int cj = coords[p * 3 + 1] >> 1;
    int ck = coords[p * 3 + 2] >> 1;
    return (ci * COARSE_RES + cj) * COARSE_RES + ck;
}

__global__ void zero_kernel(int* __restrict__ buf, int n) {
    int i = blockIdx.x * blockDim.x + threadIdx.x;
    int stride = gridDim.x * blockDim.x;
    for (; i < n; i += stride) buf[i] = 0;
}

__global__ void hist_kernel(const int* __restrict__ coords, int* __restrict__ counts, int n) {
    int p = blockIdx.x * blockDim.x + threadIdx.x;
    if (p < n) atomicAdd(&counts[seg_of(coords, p)], 1);
}

// Exclusive scan, 256 elements per block; block totals to blocksums.
__global__ void scan_block_kernel(const int* __restrict__ counts, int* __restrict__ offsets,
                                  int* __restrict__ blocksums) {
    __shared__ int tmp[256];
    int tid = threadIdx.x;
    int gid = blockIdx.x * 256 + tid;
    int v = counts[gid];
    tmp[tid] = v;
    __syncthreads();
    for (int d = 1; d < 256; d <<= 1) {
        int t = (tid >= d) ? tmp[tid - d] : 0;
        __syncthreads();
        tmp[tid] += t;
        __syncthreads();
    }
    offsets[gid] = tmp[tid] - v;  // exclusive
    if (tid == 255) blocksums[blockIdx.x] = tmp[255];
}

// Exclusive scan of the 1024 block sums, single block of 1024 threads.
__global__ void scan_sums_kernel(int* __restrict__ blocksums) {
    __shared__ int tmp[SCAN_BLOCKS];
    int tid = threadIdx.x;
    int v = blocksums[tid];
    tmp[tid] = v;
    __syncthreads();
    for (int d = 1; d < SCAN_BLOCKS; d <<= 1) {
        int t = (tid >= d) ? tmp[tid - d] : 0;
        __syncthreads();
        tmp[tid] += t;
        __syncthreads();
    }
    blocksums[tid] = tmp[tid] - v;
}

// offsets += scanned blocksums; also seed the scatter cursor.
__global__ void scan_add_kernel(int* __restrict__ offsets, int* __restrict__ cursor,
                                const int* __restrict__ blocksums) {
    int gid = blockIdx.x * 256 + threadIdx.x;
    int o = offsets[gid] + blocksums[blockIdx.x];
    offsets[gid] = o;
    cursor[gid] = o;
}

__global__ void scatter_kernel(const int* __restrict__ coords, int* __restrict__ cursor,
                               int* __restrict__ indices, int n) {
    int p = blockIdx.x * blockDim.x + threadIdx.x;
    if (p < n) {
        int pos = atomicAdd(&cursor[seg_of(coords, p)], 1);
        indices[pos] = p;
    }
}

// One wave (64 lanes) per segment; lane = channel.
__global__ void gather_max_kernel(const float* __restrict__ feat,
                                  const int* __restrict__ indices,
                                  const int* __restrict__ offsets,
                                  const int* __restrict__ counts,
                                  float* __restrict__ out) {
    int wave = (blockIdx.x * blockDim.x + threadIdx.x) >> 6;
    int lane = threadIdx.x & 63;
    if (wave >= NSEG) return;
    int beg = offsets[wave];
    int cnt = counts[wave];
    float m = -INFINITY;
    int t = 0;
    // unroll by 2 to overlap the dependent index->feature load chains
    for (; t + 2 <= cnt; t += 2) {
        int p0 = indices[beg + t];
        int p1 = indices[beg + t + 1];
        float f0 = feat[(long)p0 * CHANNELS + lane];
        float f1 = feat[(long)p1 * CHANNELS + lane];
        m = fmaxf(m, fmaxf(f0, f1));
    }
    if (t < cnt) {
        int p0 = indices[beg + t];
        m = fmaxf(m, feat[(long)p0 * CHANNELS + lane]);
    }
    out[wave * CHANNELS + lane] = (cnt == 0) ? 0.0f : m;
}

extern "C" void kernel_launch(void* const* d_in, const int* in_sizes, int n_in,
                              void* d_out, int out_size, void* d_ws, size_t ws_size,
                              hipStream_t stream) {
    const float* feat  = (const float*)d_in[0];
    const int* coords  = (const int*)d_in[1];
    int npoints = in_sizes[0] / CHANNELS;  // 1,000,000

    // Workspace layout (ints): counts | offsets | cursor | blocksums | indices
    int* ws        = (int*)d_ws;
    int* counts    = ws;
    int* offsets   = counts + NSEG;
    int* cursor    = offsets + NSEG;
    int* blocksums = cursor + NSEG;
    int* indices   = blocksums + SCAN_BLOCKS;

    const int BLOCK = 256;
    int grid_pts = (npoints + BLOCK - 1) / BLOCK;

    // A1: zero counts (+blocksums contiguous right after? not contiguous; zero separately via one pass)
    zero_kernel<<<512, BLOCK, 0, stream>>>(counts, NSEG);

    // A2: histogram
    hist_kernel<<<grid_pts, BLOCK, 0, stream>>>(coords, counts, npoints);

    // A3: exclusive scan (block partials -> scan sums -> add back + cursor seed)
    scan_block_kernel<<<SCAN_BLOCKS, 256, 0, stream>>>(counts, offsets, blocksums);
    scan_sums_kernel<<<1, SCAN_BLOCKS, 0, stream>>>(blocksums);
    scan_add_kernel<<<SCAN_BLOCKS, 256, 0, stream>>>(offsets, cursor, blocksums);

    // A4: scatter point indices into CSR
    scatter_kernel<<<grid_pts, BLOCK, 0, stream>>>(coords, cursor, indices, npoints);

    // B: gather + max, one wave per segment (4 waves per 256-thread block)
    int grid_gather = NSEG / (BLOCK / 64);  // 65536
    gather_max_kernel<<<grid_gather, BLOCK, 0, stream>>>(feat, indices, offsets, counts, (float*)d_out);
}